// Round 1
// baseline (415.066 us; speedup 1.0000x reference)
//
#include <hip/hip_runtime.h>

#define N_NODES 100000
#define N_EDGES 1600000
#define IN_DIM 256
#define OUT_DIM 128

// ---------------- GEMM: HW = H @ W ----------------
// H [N_NODES, 256] row-major, W [256, 128] row-major, HW [N_NODES, 128] fp32.
// Tile: BM=128 rows x BN=128 cols (full OUT_DIM) x BK=32.
// 256 threads, each computes 8x8 outputs. H staged TRANSPOSED in LDS
// (Hs[k][r]) so per-k fragment reads are contiguous float4 (conflict-free).
constexpr int BM = 128;
constexpr int BK = 32;
constexpr int HS_LD = BM + 4;   // pad to keep float4 alignment, break write conflicts a bit

__global__ __launch_bounds__(256, 2)
void gemm_kernel(const float* __restrict__ H, const float* __restrict__ W,
                 float* __restrict__ HW) {
    __shared__ float Hs[BK][HS_LD];   // [k][r]
    __shared__ float Ws[BK][OUT_DIM]; // [k][c]

    const int tid = threadIdx.x;
    const int block_row = blockIdx.x * BM;
    const int tx = tid & 15;          // col group 0..15
    const int ty = tid >> 4;          // row group 0..15
    const int r0 = ty * 8;
    const int c0 = tx * 8;

    float acc[8][8] = {};

    for (int kc = 0; kc < IN_DIM; kc += BK) {
        // stage H tile (transposed): 128 rows x 32 k = 1024 float4 loads
        #pragma unroll
        for (int i = 0; i < 4; ++i) {
            int r  = (tid >> 3) + i * 32;   // 0..127
            int k4 = (tid & 7) * 4;         // 0,4,...,28
            int gr = block_row + r;
            float4 v = make_float4(0.f, 0.f, 0.f, 0.f);
            if (gr < N_NODES)
                v = *(const float4*)(H + (size_t)gr * IN_DIM + kc + k4);
            Hs[k4 + 0][r] = v.x;
            Hs[k4 + 1][r] = v.y;
            Hs[k4 + 2][r] = v.z;
            Hs[k4 + 3][r] = v.w;
        }
        // stage W tile: 32 k x 128 c = 1024 float4
        #pragma unroll
        for (int i = 0; i < 4; ++i) {
            int idx = tid + i * 256;        // float4 index 0..1023
            int k   = idx >> 5;             // 32 float4 per k-row
            int c4  = (idx & 31) * 4;
            *(float4*)&Ws[k][c4] =
                *(const float4*)(W + (size_t)(kc + k) * OUT_DIM + c4);
        }
        __syncthreads();

        for (int k = 0; k < BK; ++k) {
            float a[8], b[8];
            *(float4*)&a[0] = *(const float4*)&Hs[k][r0];
            *(float4*)&a[4] = *(const float4*)&Hs[k][r0 + 4];
            *(float4*)&b[0] = *(const float4*)&Ws[k][c0];
            *(float4*)&b[4] = *(const float4*)&Ws[k][c0 + 4];
            #pragma unroll
            for (int i = 0; i < 8; ++i)
                #pragma unroll
                for (int j = 0; j < 8; ++j)
                    acc[i][j] = fmaf(a[i], b[j], acc[i][j]);
        }
        __syncthreads();
    }

    #pragma unroll
    for (int i = 0; i < 8; ++i) {
        int gr = block_row + r0 + i;
        if (gr < N_NODES) {
            float* p = HW + (size_t)gr * OUT_DIM + c0;
            *(float4*)(p)     = *(float4*)&acc[i][0];
            *(float4*)(p + 4) = *(float4*)&acc[i][4];
        }
    }
}

// ---------------- SpMM: out = A @ HW + bias ----------------
// dst is sorted -> each node's edges are a contiguous range. One wave per
// node; wave-uniform binary search finds the range; lanes hold float2 of the
// 128-dim row. Atomic-free and deterministic.
__global__ __launch_bounds__(256)
void spmm_kernel(const float* __restrict__ HW, const float* __restrict__ vals,
                 const int* __restrict__ src, const int* __restrict__ dst,
                 const float* __restrict__ bias, float* __restrict__ out) {
    const int node = blockIdx.x * 4 + (threadIdx.x >> 6);
    if (node >= N_NODES) return;
    const int lane = threadIdx.x & 63;

    // lower_bound(dst, node) and lower_bound(dst, node+1) — wave-uniform
    int l = 0, r = N_EDGES;
    while (l < r) { int m = (l + r) >> 1; if (dst[m] < node) l = m + 1; else r = m; }
    const int lo = l;
    r = N_EDGES;
    while (l < r) { int m = (l + r) >> 1; if (dst[m] < node + 1) l = m + 1; else r = m; }
    const int hi = l;

    float2 acc = make_float2(0.f, 0.f);
    const float2* __restrict__ HW2 = (const float2*)HW;
    for (int e = lo; e < hi; ++e) {
        const int   s = src[e];   // wave-uniform
        const float v = vals[e];  // wave-uniform
        float2 h = HW2[(size_t)s * 64 + lane];
        acc.x = fmaf(h.x, v, acc.x);
        acc.y = fmaf(h.y, v, acc.y);
    }
    const float2 b = ((const float2*)bias)[lane];
    float2 o;
    o.x = acc.x + b.x;
    o.y = acc.y + b.y;
    ((float2*)out)[(size_t)node * 64 + lane] = o;
}

extern "C" void kernel_launch(void* const* d_in, const int* in_sizes, int n_in,
                              void* d_out, int out_size, void* d_ws, size_t ws_size,
                              hipStream_t stream) {
    const float* H    = (const float*)d_in[0];
    const float* W    = (const float*)d_in[1];
    const float* bias = (const float*)d_in[2];
    const float* vals = (const float*)d_in[3];
    const int*   src  = (const int*)d_in[4];
    const int*   dst  = (const int*)d_in[5];
    float* out = (float*)d_out;
    float* HW  = (float*)d_ws;  // needs N_NODES*OUT_DIM*4 = 51.2 MB scratch

    gemm_kernel<<<dim3((N_NODES + BM - 1) / BM), dim3(256), 0, stream>>>(H, W, HW);
    spmm_kernel<<<dim3((N_NODES + 3) / 4), dim3(256), 0, stream>>>(HW, vals, src, dst, bias, out);
}

// Round 2
// 221.823 us; speedup vs baseline: 1.8712x; 1.8712x over previous
//
#include <hip/hip_runtime.h>

#define N_NODES 100000
#define N_EDGES 1600000
#define IN_DIM 256
#define OUT_DIM 128

// ---------------- GEMM: HW = H @ W ----------------
constexpr int BM = 128;
constexpr int BK = 32;
constexpr int HS_LD = BM + 4;

__global__ __launch_bounds__(256, 2)
void gemm_kernel(const float* __restrict__ H, const float* __restrict__ W,
                 float* __restrict__ HW) {
    __shared__ float Hs[BK][HS_LD];   // [k][r]
    __shared__ float Ws[BK][OUT_DIM]; // [k][c]

    const int tid = threadIdx.x;
    const int block_row = blockIdx.x * BM;
    const int tx = tid & 15;
    const int ty = tid >> 4;
    const int r0 = ty * 8;
    const int c0 = tx * 8;

    float acc[8][8] = {};

    for (int kc = 0; kc < IN_DIM; kc += BK) {
        #pragma unroll
        for (int i = 0; i < 4; ++i) {
            int r  = (tid >> 3) + i * 32;
            int k4 = (tid & 7) * 4;
            int gr = block_row + r;
            float4 v = make_float4(0.f, 0.f, 0.f, 0.f);
            if (gr < N_NODES)
                v = *(const float4*)(H + (size_t)gr * IN_DIM + kc + k4);
            Hs[k4 + 0][r] = v.x;
            Hs[k4 + 1][r] = v.y;
            Hs[k4 + 2][r] = v.z;
            Hs[k4 + 3][r] = v.w;
        }
        #pragma unroll
        for (int i = 0; i < 4; ++i) {
            int idx = tid + i * 256;
            int k   = idx >> 5;
            int c4  = (idx & 31) * 4;
            *(float4*)&Ws[k][c4] =
                *(const float4*)(W + (size_t)(kc + k) * OUT_DIM + c4);
        }
        __syncthreads();

        for (int k = 0; k < BK; ++k) {
            float a[8], b[8];
            *(float4*)&a[0] = *(const float4*)&Hs[k][r0];
            *(float4*)&a[4] = *(const float4*)&Hs[k][r0 + 4];
            *(float4*)&b[0] = *(const float4*)&Ws[k][c0];
            *(float4*)&b[4] = *(const float4*)&Ws[k][c0 + 4];
            #pragma unroll
            for (int i = 0; i < 8; ++i)
                #pragma unroll
                for (int j = 0; j < 8; ++j)
                    acc[i][j] = fmaf(a[i], b[j], acc[i][j]);
        }
        __syncthreads();
    }

    #pragma unroll
    for (int i = 0; i < 8; ++i) {
        int gr = block_row + r0 + i;
        if (gr < N_NODES) {
            float* p = HW + (size_t)gr * OUT_DIM + c0;
            *(float4*)(p)     = *(float4*)&acc[i][0];
            *(float4*)(p + 4) = *(float4*)&acc[i][4];
        }
    }
}

// ---------------- row_ptr from sorted dst ----------------
// row_ptr[n] = first edge e with dst[e] >= n ; row_ptr[N_NODES] = N_EDGES.
__global__ __launch_bounds__(256)
void rowptr_kernel(const int* __restrict__ dst, int* __restrict__ row_ptr) {
    const int e = blockIdx.x * blockDim.x + threadIdx.x;
    if (e > N_EDGES) return;
    if (e == N_EDGES) {
        for (int n = dst[N_EDGES - 1] + 1; n <= N_NODES; ++n) row_ptr[n] = N_EDGES;
        return;
    }
    const int d = dst[e];
    const int dprev = (e == 0) ? -1 : dst[e - 1];
    for (int n = dprev + 1; n <= d; ++n) row_ptr[n] = e;
}

// ---------------- SpMM: out = A @ HW + bias ----------------
// One wave per node; lanes hold float2 of the 128-dim row. Edge loop batched
// x8 so 8 gathers are in flight per lane. Atomic-free, deterministic.
__global__ __launch_bounds__(256)
void spmm_rp_kernel(const float* __restrict__ HW, const float* __restrict__ vals,
                    const int* __restrict__ src, const int* __restrict__ row_ptr,
                    const float* __restrict__ bias, float* __restrict__ out) {
    const int node = blockIdx.x * 4 + (threadIdx.x >> 6);
    if (node >= N_NODES) return;
    const int lane = threadIdx.x & 63;

    const int lo = row_ptr[node];
    const int hi = row_ptr[node + 1];

    float2 acc = make_float2(0.f, 0.f);
    const float2* __restrict__ HW2 = (const float2*)HW;

    int e = lo;
    for (; e + 8 <= hi; e += 8) {
        int   s[8];
        float v[8];
        #pragma unroll
        for (int j = 0; j < 8; ++j) { s[j] = src[e + j]; v[j] = vals[e + j]; }
        float2 h[8];
        #pragma unroll
        for (int j = 0; j < 8; ++j) h[j] = HW2[(size_t)s[j] * 64 + lane];
        #pragma unroll
        for (int j = 0; j < 8; ++j) {
            acc.x = fmaf(h[j].x, v[j], acc.x);
            acc.y = fmaf(h[j].y, v[j], acc.y);
        }
    }
    if (e + 4 <= hi) {
        int   s[4];
        float v[4];
        #pragma unroll
        for (int j = 0; j < 4; ++j) { s[j] = src[e + j]; v[j] = vals[e + j]; }
        float2 h[4];
        #pragma unroll
        for (int j = 0; j < 4; ++j) h[j] = HW2[(size_t)s[j] * 64 + lane];
        #pragma unroll
        for (int j = 0; j < 4; ++j) {
            acc.x = fmaf(h[j].x, v[j], acc.x);
            acc.y = fmaf(h[j].y, v[j], acc.y);
        }
        e += 4;
    }
    for (; e < hi; ++e) {
        const int   s = src[e];
        const float v = vals[e];
        float2 h = HW2[(size_t)s * 64 + lane];
        acc.x = fmaf(h.x, v, acc.x);
        acc.y = fmaf(h.y, v, acc.y);
    }

    const float2 b = ((const float2*)bias)[lane];
    float2 o;
    o.x = acc.x + b.x;
    o.y = acc.y + b.y;
    ((float2*)out)[(size_t)node * 64 + lane] = o;
}

// Fallback (binary search) if ws too small for row_ptr — unchanged semantics.
__global__ __launch_bounds__(256)
void spmm_bs_kernel(const float* __restrict__ HW, const float* __restrict__ vals,
                    const int* __restrict__ src, const int* __restrict__ dst,
                    const float* __restrict__ bias, float* __restrict__ out) {
    const int node = blockIdx.x * 4 + (threadIdx.x >> 6);
    if (node >= N_NODES) return;
    const int lane = threadIdx.x & 63;
    int l = 0, r = N_EDGES;
    while (l < r) { int m = (l + r) >> 1; if (dst[m] < node) l = m + 1; else r = m; }
    const int lo = l;
    r = N_EDGES;
    while (l < r) { int m = (l + r) >> 1; if (dst[m] < node + 1) l = m + 1; else r = m; }
    const int hi = l;
    float2 acc = make_float2(0.f, 0.f);
    const float2* __restrict__ HW2 = (const float2*)HW;
    for (int e = lo; e < hi; ++e) {
        const int   s = src[e];
        const float v = vals[e];
        float2 h = HW2[(size_t)s * 64 + lane];
        acc.x = fmaf(h.x, v, acc.x);
        acc.y = fmaf(h.y, v, acc.y);
    }
    const float2 b = ((const float2*)bias)[lane];
    ((float2*)out)[(size_t)node * 64 + lane] = make_float2(acc.x + b.x, acc.y + b.y);
}

extern "C" void kernel_launch(void* const* d_in, const int* in_sizes, int n_in,
                              void* d_out, int out_size, void* d_ws, size_t ws_size,
                              hipStream_t stream) {
    const float* H    = (const float*)d_in[0];
    const float* W    = (const float*)d_in[1];
    const float* bias = (const float*)d_in[2];
    const float* vals = (const float*)d_in[3];
    const int*   src  = (const int*)d_in[4];
    const int*   dst  = (const int*)d_in[5];
    float* out = (float*)d_out;

    float* HW = (float*)d_ws;                       // 51.2 MB
    const size_t hw_bytes = (size_t)N_NODES * OUT_DIM * sizeof(float);
    int* row_ptr = (int*)((char*)d_ws + hw_bytes);  // +400 KB
    const size_t need = hw_bytes + (size_t)(N_NODES + 1) * sizeof(int);

    gemm_kernel<<<dim3((N_NODES + BM - 1) / BM), dim3(256), 0, stream>>>(H, W, HW);

    if (ws_size >= need) {
        rowptr_kernel<<<dim3((N_EDGES + 256) / 256), dim3(256), 0, stream>>>(dst, row_ptr);
        spmm_rp_kernel<<<dim3((N_NODES + 3) / 4), dim3(256), 0, stream>>>(
            HW, vals, src, row_ptr, bias, out);
    } else {
        spmm_bs_kernel<<<dim3((N_NODES + 3) / 4), dim3(256), 0, stream>>>(
            HW, vals, src, dst, bias, out);
    }
}

// Round 4
// 130.960 us; speedup vs baseline: 3.1694x; 1.6938x over previous
//
#include <hip/hip_runtime.h>

#define N_NODES 100000
#define N_EDGES 1600000
#define IN_DIM 256
#define OUT_DIM 128

typedef __attribute__((ext_vector_type(4))) float f32x4;
typedef __attribute__((ext_vector_type(8))) short s16x8;

// fp32 -> bf16 round-to-nearest-even (finite inputs)
__device__ inline short f2bf(float f) {
    union { float f; unsigned u; } v; v.f = f;
    unsigned r = v.u + 0x7fffu + ((v.u >> 16) & 1u);
    return (short)(r >> 16);
}

__device__ inline s16x8 pack8(const float4& a, const float4& b) {
    s16x8 r;
    r[0] = f2bf(a.x); r[1] = f2bf(a.y); r[2] = f2bf(a.z); r[3] = f2bf(a.w);
    r[4] = f2bf(b.x); r[5] = f2bf(b.y); r[6] = f2bf(b.z); r[7] = f2bf(b.w);
    return r;
}

// ---------------- WT = bf16(W^T) : [col][k], 128x256 ----------------
// 32768 threads; t = k*128 + c -> coalesced W read, scattered 2B WT write
// (128 KB total, trivial).
__global__ __launch_bounds__(256)
void wt_kernel(const float* __restrict__ W, unsigned short* __restrict__ WT) {
    const int t = blockIdx.x * 256 + threadIdx.x;   // 0..32767
    const int k = t >> 7;
    const int c = t & 127;
    WT[c * IN_DIM + k] = (unsigned short)f2bf(W[t]);
}

// ---------------- GEMM: HWb(bf16) = bf16(H) @ bf16(W) via MFMA ----------------
// NO LDS. 256 threads = 4 waves; block covers 128 rows. Each wave: 32 rows.
// A-frags: fp32 H loaded per-lane, converted in regs. B-frags: 16B global
// loads from WT (64 KB, L2-resident). Pure function of (H, WT).
__global__ __launch_bounds__(256)
void gemm_mfma_kernel(const float* __restrict__ H,
                      const unsigned short* __restrict__ WT,
                      unsigned short* __restrict__ HWb) {
    const int tid  = threadIdx.x;
    const int wid  = tid >> 6;
    const int lane = tid & 63;
    const int lrow = lane & 15;   // A row within 16 / B col within 16
    const int kblk = lane >> 4;   // k sub-block 0..3 (8 elems each)
    const int wrow = blockIdx.x * 128 + wid * 32;

    int r0 = wrow + lrow;       if (r0 >= N_NODES) r0 = N_NODES - 1;
    int r1 = wrow + lrow + 16;  if (r1 >= N_NODES) r1 = N_NODES - 1;
    const float* p0 = H + (size_t)r0 * IN_DIM + kblk * 8;
    const float* p1 = H + (size_t)r1 * IN_DIM + kblk * 8;

    f32x4 acc[2][8] = {};

    // prefetch K-step 0
    float4 c00 = *(const float4*)(p0);
    float4 c01 = *(const float4*)(p0 + 4);
    float4 c10 = *(const float4*)(p1);
    float4 c11 = *(const float4*)(p1 + 4);

    #pragma unroll
    for (int kc = 0; kc < 8; ++kc) {
        const s16x8 fa0 = pack8(c00, c01);
        const s16x8 fa1 = pack8(c10, c11);
        if (kc < 7) {  // prefetch next K-step while MFMAs run
            const float* q0 = p0 + (kc + 1) * 32;
            const float* q1 = p1 + (kc + 1) * 32;
            c00 = *(const float4*)(q0);
            c01 = *(const float4*)(q0 + 4);
            c10 = *(const float4*)(q1);
            c11 = *(const float4*)(q1 + 4);
        }
        const int kbase = kc * 32 + kblk * 8;
        #pragma unroll
        for (int n = 0; n < 8; ++n) {
            const s16x8 fb =
                *(const s16x8*)(WT + (size_t)(n * 16 + lrow) * IN_DIM + kbase);
            acc[0][n] = __builtin_amdgcn_mfma_f32_16x16x32_bf16(fa0, fb, acc[0][n], 0, 0, 0);
            acc[1][n] = __builtin_amdgcn_mfma_f32_16x16x32_bf16(fa1, fb, acc[1][n], 0, 0, 0);
        }
    }

    // D layout: col = lane&15, row = (lane>>4)*4 + reg
    #pragma unroll
    for (int mt = 0; mt < 2; ++mt) {
        #pragma unroll
        for (int r = 0; r < 4; ++r) {
            const int grow = wrow + mt * 16 + (lane >> 4) * 4 + r;
            if (grow < N_NODES) {
                #pragma unroll
                for (int n = 0; n < 8; ++n)
                    HWb[(size_t)grow * OUT_DIM + n * 16 + (lane & 15)] =
                        (unsigned short)f2bf(acc[mt][n][r]);
            }
        }
    }
}

// ---------------- row_ptr from sorted dst ----------------
__global__ __launch_bounds__(256)
void rowptr_kernel(const int* __restrict__ dst, int* __restrict__ row_ptr) {
    const int e = blockIdx.x * blockDim.x + threadIdx.x;
    if (e > N_EDGES) return;
    if (e == N_EDGES) {
        for (int n = dst[N_EDGES - 1] + 1; n <= N_NODES; ++n) row_ptr[n] = N_EDGES;
        return;
    }
    const int d = dst[e];
    const int dprev = (e == 0) ? -1 : dst[e - 1];
    for (int n = dprev + 1; n <= d; ++n) row_ptr[n] = e;
}

// ---------------- SpMM: out = A @ HW(bf16) + bias ----------------
__global__ __launch_bounds__(256)
void spmm_rp_kernel(const unsigned int* __restrict__ HWu, const float* __restrict__ vals,
                    const int* __restrict__ src, const int* __restrict__ row_ptr,
                    const float* __restrict__ bias, float* __restrict__ out) {
    const int node = blockIdx.x * 4 + (threadIdx.x >> 6);
    if (node >= N_NODES) return;
    const int lane = threadIdx.x & 63;

    const int lo = row_ptr[node];
    const int hi = row_ptr[node + 1];

    float ax = 0.f, ay = 0.f;
    int e = lo;
    for (; e + 8 <= hi; e += 8) {
        int s[8]; float v[8];
        #pragma unroll
        for (int j = 0; j < 8; ++j) { s[j] = src[e + j]; v[j] = vals[e + j]; }
        unsigned p[8];
        #pragma unroll
        for (int j = 0; j < 8; ++j) p[j] = HWu[(size_t)s[j] * 64 + lane];
        #pragma unroll
        for (int j = 0; j < 8; ++j) {
            ax = fmaf(__uint_as_float(p[j] << 16), v[j], ax);
            ay = fmaf(__uint_as_float(p[j] & 0xffff0000u), v[j], ay);
        }
    }
    if (e + 4 <= hi) {
        int s[4]; float v[4];
        #pragma unroll
        for (int j = 0; j < 4; ++j) { s[j] = src[e + j]; v[j] = vals[e + j]; }
        unsigned p[4];
        #pragma unroll
        for (int j = 0; j < 4; ++j) p[j] = HWu[(size_t)s[j] * 64 + lane];
        #pragma unroll
        for (int j = 0; j < 4; ++j) {
            ax = fmaf(__uint_as_float(p[j] << 16), v[j], ax);
            ay = fmaf(__uint_as_float(p[j] & 0xffff0000u), v[j], ay);
        }
        e += 4;
    }
    for (; e < hi; ++e) {
        const unsigned p = HWu[(size_t)src[e] * 64 + lane];
        const float v = vals[e];
        ax = fmaf(__uint_as_float(p << 16), v, ax);
        ay = fmaf(__uint_as_float(p & 0xffff0000u), v, ay);
    }

    const float2 b = ((const float2*)bias)[lane];
    ((float2*)out)[(size_t)node * 64 + lane] = make_float2(ax + b.x, ay + b.y);
}

extern "C" void kernel_launch(void* const* d_in, const int* in_sizes, int n_in,
                              void* d_out, int out_size, void* d_ws, size_t ws_size,
                              hipStream_t stream) {
    const float* H    = (const float*)d_in[0];
    const float* W    = (const float*)d_in[1];
    const float* bias = (const float*)d_in[2];
    const float* vals = (const float*)d_in[3];
    const int*   src  = (const int*)d_in[4];
    const int*   dst  = (const int*)d_in[5];
    float* out = (float*)d_out;

    // ws layout: HWb bf16 [0, 25.6e6) | row_ptr [25.6e6, +400004) | WT (aligned)
    unsigned short* HWb = (unsigned short*)d_ws;
    const size_t hw_bytes = (size_t)N_NODES * OUT_DIM * sizeof(unsigned short);
    int* row_ptr = (int*)((char*)d_ws + hw_bytes);
    size_t wt_off = hw_bytes + (size_t)(N_NODES + 1) * sizeof(int);
    wt_off = (wt_off + 127) & ~(size_t)127;
    unsigned short* WT = (unsigned short*)((char*)d_ws + wt_off);

    wt_kernel<<<dim3((IN_DIM * OUT_DIM) / 256), dim3(256), 0, stream>>>(W, WT);
    rowptr_kernel<<<dim3((N_EDGES + 256) / 256), dim3(256), 0, stream>>>(dst, row_ptr);
    gemm_mfma_kernel<<<dim3((N_NODES + 127) / 128), dim3(256), 0, stream>>>(H, WT, HWb);
    spmm_rp_kernel<<<dim3((N_NODES + 3) / 4), dim3(256), 0, stream>>>(
        (const unsigned int*)HWb, vals, src, row_ptr, bias, out);
}